// Round 1
// baseline (1624.465 us; speedup 1.0000x reference)
//
#include <hip/hip_runtime.h>
#include <hip/hip_bf16.h>

// Problem constants
#define NN    8
#define CC    32
#define HH    48
#define WW    48
#define OCC   32
#define HID   256
#define FEAT  288          // C*K*K
#define RTOT  9216         // (H*S)*(W*S)
#define COLS  9216         // FEAT*OC
#define XUP   96
#define YUP   96

using bf16x8 = __attribute__((ext_vector_type(8))) __bf16;
using f32x4  = __attribute__((ext_vector_type(4))) float;

// ---------------------------------------------------------------------------
// Kernel 1: hmid = relu(v @ w1 + b1), stored bf16 in MFMA A-fragment order:
//   flat = ((r/16)*8 + k/32)*512 + ((k%32)/8)*128 + (r%16)*8 + (k%8)
// so that in the main kernel a wave loads one A frag (rows r0..r0+15, k-block)
// as a single coalesced b128 load per lane.
// ---------------------------------------------------------------------------
__global__ void prep_hmid(const float* __restrict__ v, const float* __restrict__ w1,
                          const float* __restrict__ b1, __hip_bfloat16* __restrict__ hmidp) {
  int r = blockIdx.x;      // 0..9215
  int t = threadIdx.x;     // 0..255 = hidden index k
  float v0 = v[r*3+0], v1 = v[r*3+1], v2 = v[r*3+2];
  float val = v0*w1[t] + v1*w1[HID+t] + v2*w1[2*HID+t] + b1[t];
  val = fmaxf(val, 0.0f);
  int dst = ((r>>4)*8 + (t>>5))*512 + ((t>>3)&3)*128 + (r&15)*8 + (t&7);
  hmidp[dst] = __float2bfloat16(val);
}

// ---------------------------------------------------------------------------
// Kernel 2: w2 -> bf16 in MFMA B-fragment order:
//   lane = ((k%32)/8)*16 + (col%16), flat = ((col/16)*8 + k/32)*512 + lane*8 + k%8
// ---------------------------------------------------------------------------
__global__ void prep_w2(const float* __restrict__ w2, __hip_bfloat16* __restrict__ w2p) {
  int idx = blockIdx.x*256 + threadIdx.x;   // 0 .. 256*9216-1
  int k   = idx / COLS;
  int col = idx % COLS;
  float val = w2[idx];                      // w2[k][col], row-major
  int lane = (((k>>3)&3)<<4) | (col&15);
  int dst  = (((col>>4)*8 + (k>>5))*64 + lane)*8 + (k&7);
  w2p[dst] = __float2bfloat16(val);
}

// ---------------------------------------------------------------------------
// Kernel 3: fused  W-chunk GEMM (MFMA)  +  per-pixel apply (VALU)
// One workgroup = 16 rows r (one X strip, Y0..Y0+15), 256 threads = 4 waves.
// Chunk = 16 f values = 512 W_pred columns. 18 chunks cover FEAT=288.
// ---------------------------------------------------------------------------
#define WCSTRIDE 514   // f32 stride per row; 514%8 != 0 kills cross-quarter bank conflicts

__launch_bounds__(256, 2)
__global__ void fused_main(const float* __restrict__ F_LR,
                           const __hip_bfloat16* __restrict__ hmidp,
                           const __hip_bfloat16* __restrict__ w2p,
                           const float* __restrict__ b2,
                           float* __restrict__ out) {
  __shared__ __bf16 pat[8][NN][FEAT];     // [w_local][n][f] 36,864 B
  __shared__ float  wc[16*WCSTRIDE];      // chunk W: [r][f_local*32+oc], 32,896 B

  const int tid  = threadIdx.x;
  const int lane = tid & 63;
  const int wv   = tid >> 6;              // wave 0..3
  const int blk  = blockIdx.x;            // 0..575
  const int X    = blk / 6;
  const int Y0   = (blk % 6) * 16;
  const int h    = X >> 1;
  const int w0   = Y0 >> 1;

  // ---- A fragments: hmid rows r0..r0+15, all K=256, kept in registers ----
  bf16x8 a[8];
  {
    const bf16x8* ap = reinterpret_cast<const bf16x8*>(hmidp) + (blk*8)*64 + lane;
    #pragma unroll
    for (int kb = 0; kb < 8; ++kb) a[kb] = ap[kb*64];
  }

  // ---- stage patches: pat[wl][n][c*9+ki*3+kj] = F_LR[n,c,h-1+ki,(w0+wl)-1+kj] ----
  for (int idx = tid; idx < NN*CC*3*10; idx += 256) {
    int cc = idx % 10;
    int rr = (idx/10) % 3;
    int c  = (idx/30) % CC;
    int n  = idx/(30*CC);
    int hh = h - 1 + rr;
    int ww = w0 - 1 + cc;
    float val = 0.0f;
    if (hh >= 0 && hh < HH && ww >= 0 && ww < WW)
      val = F_LR[((n*CC + c)*HH + hh)*WW + ww];
    __bf16 bv = (__bf16)val;
    #pragma unroll
    for (int kj = 0; kj < 3; ++kj) {
      int wl = cc - kj;
      if (wl >= 0 && wl < 8)
        pat[wl][n][c*9 + rr*3 + kj] = bv;
    }
  }

  float oacc[4][4];                        // [row_local_in_wave][n_sub]
  #pragma unroll
  for (int i = 0; i < 4; ++i)
    #pragma unroll
    for (int j = 0; j < 4; ++j) oacc[i][j] = 0.f;

  const int oc_l = lane & 31;
  const int ngrp = lane >> 5;              // n = ngrp*4 + q

  __syncthreads();

  for (int ch = 0; ch < 18; ++ch) {
    const int colbase = ch*512 + wv*128;   // this wave's 128 columns of the chunk

    // ---- GEMM: Wc[16 x 128] = hmid_tile @ w2[:, cols] + b2 ----
    f32x4 acc[8];
    #pragma unroll
    for (int nfl = 0; nfl < 8; ++nfl) {
      float bb = b2[colbase + nfl*16 + (lane & 15)];
      acc[nfl][0] = bb; acc[nfl][1] = bb; acc[nfl][2] = bb; acc[nfl][3] = bb;
    }
    {
      const bf16x8* bp = reinterpret_cast<const bf16x8*>(w2p) + ((colbase>>4)*8)*64 + lane;
      #pragma unroll 2
      for (int kb = 0; kb < 8; ++kb) {
        #pragma unroll
        for (int nfl = 0; nfl < 8; ++nfl) {
          bf16x8 b = bp[(nfl*8 + kb)*64];
          acc[nfl] = __builtin_amdgcn_mfma_f32_16x16x32_bf16(a[kb], b, acc[nfl], 0, 0, 0);
        }
      }
    }
    // ---- spill chunk W to LDS (f32). C-frag: col=lane&15, row=(lane>>4)*4+j ----
    #pragma unroll
    for (int nfl = 0; nfl < 8; ++nfl) {
      int col = colbase + nfl*16 + (lane & 15);
      int fl  = (col >> 5) & 15;           // f within chunk
      int oc  = col & 31;
      int rb  = (lane >> 4) * 4;
      #pragma unroll
      for (int j = 0; j < 4; ++j)
        wc[(rb + j)*WCSTRIDE + fl*32 + oc] = acc[nfl][j];
    }
    __syncthreads();

    // ---- apply: out[n,r,oc] += sum_f pat[n,f,l(r)] * Wc[r,f,oc] ----
    // wave wv owns local rows wv*4 .. wv*4+3 (row pairs share w_local)
    #pragma unroll
    for (int pr = 0; pr < 2; ++pr) {
      const int wl = wv*2 + pr;
      float p[4][16];
      #pragma unroll
      for (int q = 0; q < 4; ++q) {
        int n = ngrp*4 + q;
        const bf16x8* pp = reinterpret_cast<const bf16x8*>(&pat[wl][n][ch*16]);
        bf16x8 p0 = pp[0], p1 = pp[1];
        #pragma unroll
        for (int i = 0; i < 8; ++i) { p[q][i] = (float)p0[i]; p[q][8+i] = (float)p1[i]; }
      }
      #pragma unroll
      for (int rr = 0; rr < 2; ++rr) {
        const int r = wv*4 + pr*2 + rr;
        float s0 = 0.f, s1 = 0.f, s2 = 0.f, s3 = 0.f;
        #pragma unroll
        for (int f = 0; f < 16; ++f) {
          float wval = wc[r*WCSTRIDE + f*32 + oc_l];
          s0 += wval * p[0][f];
          s1 += wval * p[1][f];
          s2 += wval * p[2][f];
          s3 += wval * p[3][f];
        }
        oacc[pr*2+rr][0] += s0;
        oacc[pr*2+rr][1] += s1;
        oacc[pr*2+rr][2] += s2;
        oacc[pr*2+rr][3] += s3;
      }
    }
    __syncthreads();
  }

  // ---- epilogue: out[n, oc, X, Y0+wv*4 .. +3], float4 per (n) ----
  #pragma unroll
  for (int q = 0; q < 4; ++q) {
    int n = ngrp*4 + q;
    f32x4 vals;
    vals[0] = oacc[0][q]; vals[1] = oacc[1][q]; vals[2] = oacc[2][q]; vals[3] = oacc[3][q];
    float* dst = out + ((size_t)(n*OCC + oc_l)*XUP + X)*YUP + Y0 + wv*4;
    *reinterpret_cast<f32x4*>(dst) = vals;
  }
}

// ---------------------------------------------------------------------------
extern "C" void kernel_launch(void* const* d_in, const int* in_sizes, int n_in,
                              void* d_out, int out_size, void* d_ws, size_t ws_size,
                              hipStream_t stream) {
  const float* F_LR = (const float*)d_in[0];
  const float* v    = (const float*)d_in[1];
  const float* w1   = (const float*)d_in[2];
  const float* b1   = (const float*)d_in[3];
  const float* w2   = (const float*)d_in[4];
  const float* b2   = (const float*)d_in[5];
  float* out = (float*)d_out;

  __hip_bfloat16* hmidp = (__hip_bfloat16*)d_ws;                                  // 4,718,592 B
  __hip_bfloat16* w2p   = (__hip_bfloat16*)((char*)d_ws + (size_t)RTOT*HID*2);    // 4,718,592 B

  hipLaunchKernelGGL(prep_hmid, dim3(RTOT), dim3(HID), 0, stream, v, w1, b1, hmidp);
  hipLaunchKernelGGL(prep_w2,   dim3((HID*COLS)/256), dim3(256), 0, stream, w2, w2p);
  hipLaunchKernelGGL(fused_main, dim3(576), dim3(256), 0, stream, F_LR, hmidp, w2p, b2, out);
}

// Round 2
// 420.994 us; speedup vs baseline: 3.8586x; 3.8586x over previous
//
#include <hip/hip_runtime.h>
#include <hip/hip_bf16.h>

// Problem constants
#define NN    8
#define CC    32
#define HH    48
#define WW    48
#define OCC   32
#define HID   256
#define FEAT  288          // C*K*K
#define RTOT  9216         // (H*S)*(W*S)
#define COLS  9216         // FEAT*OC
#define XUP   96
#define YUP   96
#define OUTSZ (NN*OCC*XUP*YUP)   // 2,359,296 floats

using bf16x8 = __attribute__((ext_vector_type(8))) __bf16;
using f32x4  = __attribute__((ext_vector_type(4))) float;

#define GLOAD_LDS16(gp, lp)                                                        \
  __builtin_amdgcn_global_load_lds((const __attribute__((address_space(1))) void*)(gp), \
                                   (__attribute__((address_space(3))) void*)(lp), 16, 0, 0)

// ---------------------------------------------------------------------------
// Kernel 1: hmid = relu(v @ w1 + b1), bf16, MFMA A-fragment order (verified r1):
//   frag = (r/16)*8 + k/32 ; lane = ((k/8)%4)*16 + r%16 ; elem = k%8
//   flat = frag*512 + lane*8 + elem
// ---------------------------------------------------------------------------
__global__ void prep_hmid(const float* __restrict__ v, const float* __restrict__ w1,
                          const float* __restrict__ b1, __hip_bfloat16* __restrict__ hmidp) {
  int r = blockIdx.x;      // 0..9215
  int t = threadIdx.x;     // 0..255 = hidden index k
  float v0 = v[r*3+0], v1 = v[r*3+1], v2 = v[r*3+2];
  float val = v0*w1[t] + v1*w1[HID+t] + v2*w1[2*HID+t] + b1[t];
  val = fmaxf(val, 0.0f);
  int dst = ((r>>4)*8 + (t>>5))*512 + ((t>>3)&3)*128 + (r&15)*8 + (t&7);
  hmidp[dst] = __float2bfloat16(val);
}

// ---------------------------------------------------------------------------
// Kernel 2: w2 -> bf16, B-fragment order grouped into 8KB slices:
//   colchunk = col/128 (72), kb = k/32 (8), cg = (col%128)/16 (8),
//   lane = ((k/8)%4)*16 + col%16, elem = k%8
//   slice (colchunk,kb) is 8192B contiguous -> global_load_lds-able linearly.
// ---------------------------------------------------------------------------
__global__ void prep_w2(const float* __restrict__ w2, __hip_bfloat16* __restrict__ w2p) {
  int idx = blockIdx.x*256 + threadIdx.x;   // 0 .. 256*9216-1
  int k   = idx / COLS;
  int col = idx % COLS;
  float val = w2[idx];                      // w2[k][col], row-major
  int colchunk = col >> 7;
  int cg   = (col >> 4) & 7;
  int lane = (((k>>3)&3)<<4) | (col & 15);
  int kb   = k >> 5;
  int i    = k & 7;
  int dst  = (((colchunk*8 + kb)*8 + cg)*64 + lane)*8 + i;
  w2p[dst] = __float2bfloat16(val);
}

// ---------------------------------------------------------------------------
// Kernel 3: fused GEMM (global_load_lds dbuf) + VALU apply.
// Block = 32 rows (one X, 32 consecutive Y) x col-group g. 256 thr = 4 waves.
// Chunk = 128 cols (4 f). K=256 in 8 slices of 32k (8KB each, ring of 2).
// LDS: A 16K + Bs 16K + wc 16K + pat 27.6K = 76.8KB -> 2 blocks/CU.
// ---------------------------------------------------------------------------
__launch_bounds__(256, 2)
__global__ void fused_main(const float* __restrict__ F_LR,
                           const __hip_bfloat16* __restrict__ hmidp,
                           const __hip_bfloat16* __restrict__ w2p,
                           const float* __restrict__ b2,
                           float* __restrict__ outp,
                           int G, int nch) {
  __shared__ __align__(16) __bf16 Atile[16*64*8];      // [mg*8+kb][lane][8]   16384B
  __shared__ __align__(16) __bf16 Bs[2][8*64*8];       // 2 slices x 8192B
  __shared__ __align__(16) float  wc[32*128];          // XOR-swizzled         16384B
  __shared__ __align__(16) __bf16 pat[NN][CC][3][18];  //                      27648B

  const int tid  = threadIdx.x;
  const int lane = tid & 63;
  const int wv   = tid >> 6;
  const int blk  = blockIdx.x;
  const int rowtile = blk / G;            // 0..287
  const int g       = blk - rowtile*G;
  const int X  = rowtile / 3;
  const int Yh = rowtile - X*3;
  const int h  = X >> 1;
  const int w0 = Yh * 16;
  const int oc  = lane & 31;
  const int nh  = lane >> 5;
  const int l15 = lane & 15;
  const int nslices = nch*8;

  const char* w2pB = (const char*)w2p + (size_t)g*nch*65536;  // this group's slices

  // ---- stage A tile (16KB, linear) ----
  {
    const char* hsrc = (const char*)hmidp + (size_t)rowtile*16384;
    char* Ab = (char*)Atile;
    #pragma unroll
    for (int j = 0; j < 4; ++j)
      GLOAD_LDS16(hsrc + wv*1024 + j*4096 + lane*16, Ab + wv*1024 + j*4096);
  }
  // ---- stage first B slice ----
  char* BsB = (char*)Bs;
  auto stage_slice = [&](int ts, int buf) {
    const char* src = w2pB + (size_t)ts*8192;
    GLOAD_LDS16(src + wv*1024 + lane*16,        BsB + buf*8192 + wv*1024);
    GLOAD_LDS16(src + 4096 + wv*1024 + lane*16, BsB + buf*8192 + 4096 + wv*1024);
  };
  stage_slice(0, 0);

  // ---- stage raw patch: pat[n][c][ki][wi] = F_LR[n,c,h-1+ki,w0-1+wi] ----
  for (int idx = tid; idx < NN*CC*3*18; idx += 256) {
    int wi = idx % 18;
    int t2 = idx / 18;
    int ki = t2 % 3;
    int t3 = t2 / 3;
    int c  = t3 & 31;
    int n  = t3 >> 5;
    int hh = h - 1 + ki;
    int ww = w0 - 1 + wi;
    float val = 0.f;
    if ((unsigned)hh < (unsigned)HH && (unsigned)ww < (unsigned)WW)
      val = F_LR[((n*CC + c)*HH + hh)*WW + ww];
    pat[n][c][ki][wi] = (__bf16)val;
  }

  float oacc[8][4];
  #pragma unroll
  for (int i = 0; i < 8; ++i)
    { oacc[i][0]=0.f; oacc[i][1]=0.f; oacc[i][2]=0.f; oacc[i][3]=0.f; }

  int t = 0;
  for (int ch = 0; ch < nch; ++ch) {
    const int colbase = (g*nch + ch)*128;
    const float bb0 = b2[colbase + wv*32 + l15];
    const float bb1 = b2[colbase + wv*32 + 16 + l15];
    f32x4 acc00 = {bb0,bb0,bb0,bb0}, acc10 = acc00;
    f32x4 acc01 = {bb1,bb1,bb1,bb1}, acc11 = acc01;

    #pragma unroll
    for (int s = 0; s < 8; ++s, ++t) {
      __syncthreads();                       // stage(t) complete; prev buf free
      if (t + 1 < nslices) stage_slice(t+1, (t+1)&1);
      const char* bufp = BsB + (size_t)(t&1)*8192;
      bf16x8 a0 = *(const bf16x8*)((const char*)Atile + (size_t)(s*64 + lane)*16);
      bf16x8 a1 = *(const bf16x8*)((const char*)Atile + (size_t)((8+s)*64 + lane)*16);
      bf16x8 b0 = *(const bf16x8*)(bufp + (size_t)((wv*2+0)*64 + lane)*16);
      bf16x8 b1 = *(const bf16x8*)(bufp + (size_t)((wv*2+1)*64 + lane)*16);
      acc00 = __builtin_amdgcn_mfma_f32_16x16x32_bf16(a0, b0, acc00, 0,0,0);
      acc01 = __builtin_amdgcn_mfma_f32_16x16x32_bf16(a0, b1, acc01, 0,0,0);
      acc10 = __builtin_amdgcn_mfma_f32_16x16x32_bf16(a1, b0, acc10, 0,0,0);
      acc11 = __builtin_amdgcn_mfma_f32_16x16x32_bf16(a1, b1, acc11, 0,0,0);
    }

    // ---- spill chunk W to LDS (XOR swizzle => writes 2-way, reads free) ----
    const int qt = lane >> 4;
    #pragma unroll
    for (int mg = 0; mg < 2; ++mg) {
      #pragma unroll
      for (int ng = 0; ng < 2; ++ng) {
        f32x4 A = (mg==0) ? (ng==0?acc00:acc01) : (ng==0?acc10:acc11);
        int ccol = wv*32 + ng*16 + l15;
        #pragma unroll
        for (int j = 0; j < 4; ++j) {
          int r = mg*16 + qt*4 + j;
          wc[r*128 + (ccol ^ ((r&7)<<2))] = A[j];
        }
      }
    }
    __syncthreads();

    // ---- apply: oacc[r'][q] += wc[r][f*32+oc] * pat[n][c][ki][(r>>1)+kj] ----
    const int fb = (g*nch + ch)*4;
    #pragma unroll
    for (int fl = 0; fl < 4; ++fl) {
      const int f   = fb + fl;
      const int c   = f / 9;
      const int rem = f - c*9;
      const int ki  = rem / 3;
      const int kj  = rem - ki*3;
      const __bf16* pb = &pat[0][0][0][0] + (c*3 + ki)*18 + kj;
      #pragma unroll
      for (int rp = 0; rp < 4; ++rp) {
        const int r0 = wv*8 + rp*2;
        float w0v = wc[r0*128     + ((fl*32 + oc) ^ ((r0&7)<<2))];
        float w1v = wc[(r0+1)*128 + ((fl*32 + oc) ^ (((r0+1)&7)<<2))];
        const __bf16* pp = pb + (r0 >> 1);
        #pragma unroll
        for (int q = 0; q < 4; ++q) {
          float pv = (float)pp[(nh*4+q)*1728];
          oacc[rp*2][q]   += w0v * pv;
          oacc[rp*2+1][q] += w1v * pv;
        }
      }
    }
  }

  // ---- epilogue: Y-contiguous f32x4 stores ----
  float* OP = outp + (size_t)g*OUTSZ;
  #pragma unroll
  for (int q = 0; q < 4; ++q) {
    int n = nh*4 + q;
    f32x4 v0, v1;
    v0[0]=oacc[0][q]; v0[1]=oacc[1][q]; v0[2]=oacc[2][q]; v0[3]=oacc[3][q];
    v1[0]=oacc[4][q]; v1[1]=oacc[5][q]; v1[2]=oacc[6][q]; v1[3]=oacc[7][q];
    float* dst = OP + (((size_t)(n*OCC + oc)*XUP + X)*YUP + Yh*32 + wv*8);
    *(f32x4*)dst     = v0;
    *(f32x4*)(dst+4) = v1;
  }
}

// ---------------------------------------------------------------------------
// Kernel 4 (G=2 only): out = P0 + P1 (deterministic, no atomics)
// ---------------------------------------------------------------------------
__global__ void reduce2(const float* __restrict__ P, float* __restrict__ out) {
  int i = blockIdx.x*256 + threadIdx.x;
  if (i < OUTSZ/4) {
    f32x4 a = ((const f32x4*)P)[i];
    f32x4 b = ((const f32x4*)(P + OUTSZ))[i];
    ((f32x4*)out)[i] = a + b;
  }
}

// ---------------------------------------------------------------------------
extern "C" void kernel_launch(void* const* d_in, const int* in_sizes, int n_in,
                              void* d_out, int out_size, void* d_ws, size_t ws_size,
                              hipStream_t stream) {
  const float* F_LR = (const float*)d_in[0];
  const float* v    = (const float*)d_in[1];
  const float* w1   = (const float*)d_in[2];
  const float* b1   = (const float*)d_in[3];
  const float* w2   = (const float*)d_in[4];
  const float* b2   = (const float*)d_in[5];
  float* out = (float*)d_out;

  const size_t prepBytes = (size_t)RTOT*HID*2;          // 4,718,592 each
  const size_t need2 = 2*prepBytes + 2ull*OUTSZ*4;      // 28,311,552
  const int G   = (ws_size >= need2) ? 2 : 1;
  const int nch = 72 / G;

  __hip_bfloat16* hmidp = (__hip_bfloat16*)d_ws;
  __hip_bfloat16* w2p   = (__hip_bfloat16*)((char*)d_ws + prepBytes);
  float* P = (float*)((char*)d_ws + 2*prepBytes);
  float* target = (G == 2) ? P : out;

  hipLaunchKernelGGL(prep_hmid, dim3(RTOT), dim3(HID), 0, stream, v, w1, b1, hmidp);
  hipLaunchKernelGGL(prep_w2,   dim3((HID*COLS)/256), dim3(256), 0, stream, w2, w2p);
  hipLaunchKernelGGL(fused_main, dim3(288*G), dim3(256), 0, stream,
                     F_LR, hmidp, w2p, b2, target, G, nch);
  if (G == 2)
    hipLaunchKernelGGL(reduce2, dim3(OUTSZ/4/256), dim3(256), 0, stream, P, out);
}

// Round 4
// 199.940 us; speedup vs baseline: 8.1248x; 2.1056x over previous
//
#include <hip/hip_runtime.h>
#include <hip/hip_bf16.h>

// Problem constants
#define NN    8
#define CC    32
#define HH    48
#define WW    48
#define OCC   32
#define HID   256
#define FEAT  288          // C*K*K
#define RTOT  9216         // (H*S)*(W*S)
#define COLS  9216         // FEAT*OC
#define XUP   96
#define YUP   96
#define OUTSZ (NN*OCC*XUP*YUP)   // 2,359,296 floats

using bf16x8 = __attribute__((ext_vector_type(8))) __bf16;
using bf16x4 = __attribute__((ext_vector_type(4))) __bf16;
using f32x4  = __attribute__((ext_vector_type(4))) float;

#define GLOAD_LDS16(gp, lp)                                                        \
  __builtin_amdgcn_global_load_lds((const __attribute__((address_space(1))) void*)(gp), \
                                   (__attribute__((address_space(3))) void*)(lp), 16, 0, 0)

// ---------------------------------------------------------------------------
// Kernel 1: hmid = relu(v @ w1 + b1), bf16, MFMA A-fragment order (verified):
//   frag = (r/16)*8 + k/32 ; lane = ((k/8)%4)*16 + r%16 ; elem = k%8
// ---------------------------------------------------------------------------
__global__ void prep_hmid(const float* __restrict__ v, const float* __restrict__ w1,
                          const float* __restrict__ b1, __hip_bfloat16* __restrict__ hmidp) {
  int r = blockIdx.x;      // 0..9215
  int t = threadIdx.x;     // 0..255 = hidden index k
  float v0 = v[r*3+0], v1 = v[r*3+1], v2 = v[r*3+2];
  float val = v0*w1[t] + v1*w1[HID+t] + v2*w1[2*HID+t] + b1[t];
  val = fmaxf(val, 0.0f);
  int dst = ((r>>4)*8 + (t>>5))*512 + ((t>>3)&3)*128 + (r&15)*8 + (t&7);
  hmidp[dst] = __float2bfloat16(val);
}

// ---------------------------------------------------------------------------
// Kernel 2: w2 -> bf16, B-fragment order; slice (colchunk,kb) = 8192B contiguous,
// inside: cg (16-col group) * 1024B, then lane*16B.
// ---------------------------------------------------------------------------
__global__ void prep_w2(const float* __restrict__ w2, __hip_bfloat16* __restrict__ w2p) {
  int idx = blockIdx.x*256 + threadIdx.x;   // 0 .. 256*9216-1
  int k   = idx / COLS;
  int col = idx % COLS;
  float val = w2[idx];                      // w2[k][col], row-major
  int colchunk = col >> 7;
  int cg   = (col >> 4) & 7;
  int lane = (((k>>3)&3)<<4) | (col & 15);
  int kb   = k >> 5;
  int i    = k & 7;
  int dst  = (((colchunk*8 + kb)*8 + cg)*64 + lane)*8 + i;
  w2p[dst] = __float2bfloat16(val);
}

// ---------------------------------------------------------------------------
// Kernel 3: fused GEMM + apply. Counted-vmcnt pipeline, 2 barriers/chunk.
// Block = 32 rows (one X, 32 Y) x col-group g; 256 thr = 4 waves.
// Each wave stages AND consumes its own B quarter -> no barriers for B.
// TAIL FIX: dummy stages keep exactly 3 slices (6 loads) in the vmem FIFO at
// every vmcnt(4), so the wait always drains through slice t.
// ---------------------------------------------------------------------------
__launch_bounds__(256, 2)
__global__ void fused_main(const float* __restrict__ F_LR,
                           const __hip_bfloat16* __restrict__ hmidp,
                           const __hip_bfloat16* __restrict__ w2p,
                           const float* __restrict__ b2,
                           float* __restrict__ outp,
                           int G, int nch) {
  __shared__ __align__(16) __bf16 pat[CC][3][18][NN];   // 27648B [c][ki][wi][n]
  __shared__ __align__(16) float  wc[4*OCC*32];         // 16384B [f][oc][r^swz]
  __shared__ __align__(16) __bf16 Bring[4*4096];        // 32768B ring of 4 slices
  __shared__ __align__(16) float  biasb[256];           //  1024B (2 chunks)
  __shared__ __align__(16) char   dummy[2048];          //  dead sink for tail stages

  const int tid  = threadIdx.x;
  const int lane = tid & 63;
  const int wv   = tid >> 6;
  const int blk  = blockIdx.x;
  const int rowtile = blk / G;            // 0..287
  const int g       = blk - rowtile*G;    // g parity == XCD parity (L2 pinning)
  const int X  = rowtile / 3;
  const int Yh = rowtile - X*3;
  const int h  = X >> 1;
  const int w0 = Yh * 16;
  const int l15 = lane & 15;
  const int qt  = lane >> 4;
  const int oc  = lane & 31;
  const int nh  = lane >> 5;
  const int colchunk0 = g*nch;
  const int NT = nch*8;

  // ---- B stage: wave wv stages its own 2KB quarter of slice t ----
  const char* w2base = (const char*)w2p + (size_t)colchunk0*65536;
  char* BringB = (char*)Bring;
  auto stage_any = [&](int t) {
    if (t < NT) {
      const char* src = w2base + (size_t)t*8192 + wv*2048 + lane*16;
      char* dst = BringB + (t&3)*8192 + wv*2048;
      GLOAD_LDS16(src, dst);
      GLOAD_LDS16(src + 1024, dst + 1024);
    } else {   // dummy: keep FIFO depth invariant; nobody reads `dummy`
      const char* src = w2base + wv*2048 + lane*16;
      GLOAD_LDS16(src, (char*)dummy);
      GLOAD_LDS16(src + 1024, (char*)dummy + 1024);
    }
  };
  stage_any(0); stage_any(1); stage_any(2);
  asm volatile("" ::: "memory");   // pin: stages are the 6 oldest vmem ops

  // ---- A fragments -> registers (16 coalesced b128 loads) ----
  bf16x8 a[2][8];
  {
    const bf16x8* ap = reinterpret_cast<const bf16x8*>(hmidp) + (size_t)rowtile*1024 + lane;
    #pragma unroll
    for (int mg = 0; mg < 2; ++mg)
      #pragma unroll
      for (int kb = 0; kb < 8; ++kb) a[mg][kb] = ap[(mg*8 + kb)*64];
  }

  // ---- stage patches: pat[c][ki][wi][n]; thread = (n,c) ----
  {
    const int n = tid >> 5, c = tid & 31;
    const float* fsrc = F_LR + ((size_t)(n*CC + c)*HH)*WW;
    #pragma unroll
    for (int ki = 0; ki < 3; ++ki) {
      int hh = h - 1 + ki;
      bool hok = (unsigned)hh < (unsigned)HH;
      #pragma unroll
      for (int wi = 0; wi < 18; ++wi) {
        int ww = w0 - 1 + wi;
        float val = (hok && (unsigned)ww < (unsigned)WW) ? fsrc[hh*WW + ww] : 0.f;
        pat[c][ki][wi][n] = (__bf16)val;
      }
    }
  }
  asm volatile("s_waitcnt lgkmcnt(0)" ::: "memory");
  __builtin_amdgcn_sched_barrier(0);
  __builtin_amdgcn_s_barrier();

  float oacc[8][4];
  #pragma unroll
  for (int i = 0; i < 8; ++i)
    { oacc[i][0]=0.f; oacc[i][1]=0.f; oacc[i][2]=0.f; oacc[i][3]=0.f; }

  for (int ch = 0; ch < nch; ++ch) {
    if ((ch & 1) == 0) {   // bias for (ch, ch+1): 1024B, all waves redundantly (same data)
      const char* bsrc = (const char*)(b2 + (size_t)(colchunk0 + ch)*128) + lane*16;
      GLOAD_LDS16(bsrc, (char*)biasb);
    }

    f32x4 acc00 = {0,0,0,0}, acc01 = {0,0,0,0}, acc10 = {0,0,0,0}, acc11 = {0,0,0,0};

    #pragma unroll
    for (int s = 0; s < 8; ++s) {
      const int t = ch*8 + s;
      asm volatile("s_waitcnt vmcnt(4)" ::: "memory");   // slice t landed (t+1,t+2 in flight)
      const char* bufp = BringB + (size_t)(t&3)*8192 + wv*2048;
      bf16x8 b0 = *(const bf16x8*)(bufp + lane*16);
      bf16x8 b1 = *(const bf16x8*)(bufp + 1024 + lane*16);
      stage_any(t + 3);
      acc00 = __builtin_amdgcn_mfma_f32_16x16x32_bf16(a[0][s], b0, acc00, 0,0,0);
      acc01 = __builtin_amdgcn_mfma_f32_16x16x32_bf16(a[0][s], b1, acc01, 0,0,0);
      acc10 = __builtin_amdgcn_mfma_f32_16x16x32_bf16(a[1][s], b0, acc10, 0,0,0);
      acc11 = __builtin_amdgcn_mfma_f32_16x16x32_bf16(a[1][s], b1, acc11, 0,0,0);
    }

    // ---- wc write: wc[wv][oc][r^swz] = acc + bias ----
    asm volatile("s_waitcnt vmcnt(6)" ::: "memory");     // bias GLOAD (older) complete
    {
      float bias0 = biasb[(ch&1)*128 + wv*32 + l15];
      float bias1 = biasb[(ch&1)*128 + wv*32 + 16 + l15];
      #pragma unroll
      for (int mg = 0; mg < 2; ++mg) {
        #pragma unroll
        for (int ng = 0; ng < 2; ++ng) {
          f32x4 A = (mg==0) ? (ng==0?acc00:acc01) : (ng==0?acc10:acc11);
          float bb = ng ? bias1 : bias0;
          A[0]+=bb; A[1]+=bb; A[2]+=bb; A[3]+=bb;
          int ocx  = ng*16 + l15;
          int ridx = (mg*16 + qt*4) ^ ((ocx&7)<<2);
          *(f32x4*)&wc[wv*1024 + ocx*32 + ridx] = A;
        }
      }
    }
    asm volatile("s_waitcnt lgkmcnt(0)" ::: "memory");
    __builtin_amdgcn_sched_barrier(0);
    __builtin_amdgcn_s_barrier();                        // wc visible (vmcnt NOT drained)

    // ---- apply ----
    const int swz = (oc & 7) << 2;
    #pragma unroll
    for (int fl = 0; fl < 4; ++fl) {
      const int f   = (colchunk0 + ch)*4 + fl;
      const int c   = f / 9;
      const int rem = f - c*9;
      const int ki  = rem / 3;
      const int kj  = rem - ki*3;
      const f32x4 wlo = *(const f32x4*)&wc[fl*1024 + oc*32 + ((wv*8    ) ^ swz)];
      const f32x4 whi = *(const f32x4*)&wc[fl*1024 + oc*32 + ((wv*8 + 4) ^ swz)];
      const __bf16* pbase = &pat[c][ki][0][0] + nh*4;
      #pragma unroll
      for (int rrh = 0; rrh < 4; ++rrh) {
        bf16x4 pq = *(const bf16x4*)(pbase + (wv*4 + rrh + kj)*8);
        float w0v = (rrh < 2) ? ((rrh == 0) ? wlo[0] : wlo[2]) : ((rrh == 2) ? whi[0] : whi[2]);
        float w1v = (rrh < 2) ? ((rrh == 0) ? wlo[1] : wlo[3]) : ((rrh == 2) ? whi[1] : whi[3]);
        #pragma unroll
        for (int q = 0; q < 4; ++q) {
          float pv = (float)pq[q];
          oacc[rrh*2][q]   += w0v * pv;
          oacc[rrh*2+1][q] += w1v * pv;
        }
      }
    }
    asm volatile("s_waitcnt lgkmcnt(0)" ::: "memory");
    __builtin_amdgcn_sched_barrier(0);
    __builtin_amdgcn_s_barrier();                        // apply done; wc reusable
  }

  // ---- epilogue: out[n, oc, X, Yh*32 + wv*8 .. +7] ----
  float* OP = outp + (size_t)g*OUTSZ;
  #pragma unroll
  for (int q = 0; q < 4; ++q) {
    int n = nh*4 + q;
    f32x4 v0, v1;
    v0[0]=oacc[0][q]; v0[1]=oacc[1][q]; v0[2]=oacc[2][q]; v0[3]=oacc[3][q];
    v1[0]=oacc[4][q]; v1[1]=oacc[5][q]; v1[2]=oacc[6][q]; v1[3]=oacc[7][q];
    float* dst = OP + (((size_t)(n*OCC + oc)*XUP + X)*YUP + Yh*32 + wv*8);
    *(f32x4*)dst     = v0;
    *(f32x4*)(dst+4) = v1;
  }
}

// ---------------------------------------------------------------------------
// Kernel 4 (G=2 only): out = P0 + P1 (deterministic)
// ---------------------------------------------------------------------------
__global__ void reduce2(const float* __restrict__ P, float* __restrict__ out) {
  int i = blockIdx.x*256 + threadIdx.x;
  if (i < OUTSZ/4) {
    f32x4 a = ((const f32x4*)P)[i];
    f32x4 b = ((const f32x4*)(P + OUTSZ))[i];
    ((f32x4*)out)[i] = a + b;
  }
}

// ---------------------------------------------------------------------------
extern "C" void kernel_launch(void* const* d_in, const int* in_sizes, int n_in,
                              void* d_out, int out_size, void* d_ws, size_t ws_size,
                              hipStream_t stream) {
  const float* F_LR = (const float*)d_in[0];
  const float* v    = (const float*)d_in[1];
  const float* w1   = (const float*)d_in[2];
  const float* b1   = (const float*)d_in[3];
  const float* w2   = (const float*)d_in[4];
  const float* b2   = (const float*)d_in[5];
  float* out = (float*)d_out;

  const size_t prepBytes = (size_t)RTOT*HID*2;          // 4,718,592 each
  const size_t need2 = 2*prepBytes + 2ull*OUTSZ*4;      // 28,311,552
  const int G   = (ws_size >= need2) ? 2 : 1;
  const int nch = 72 / G;

  __hip_bfloat16* hmidp = (__hip_bfloat16*)d_ws;
  __hip_bfloat16* w2p   = (__hip_bfloat16*)((char*)d_ws + prepBytes);
  float* P = (float*)((char*)d_ws + 2*prepBytes);
  float* target = (G == 2) ? P : out;

  hipLaunchKernelGGL(prep_hmid, dim3(RTOT), dim3(HID), 0, stream, v, w1, b1, hmidp);
  hipLaunchKernelGGL(prep_w2,   dim3((HID*COLS)/256), dim3(256), 0, stream, w2, w2p);
  hipLaunchKernelGGL(fused_main, dim3(288*G), dim3(256), 0, stream,
                     F_LR, hmidp, w2p, b2, target, G, nch);
  if (G == 2)
    hipLaunchKernelGGL(reduce2, dim3(OUTSZ/4/256), dim3(256), 0, stream, P, out);
}